// Round 1
// baseline (197.744 us; speedup 1.0000x reference)
//
#include <hip/hip_runtime.h>

// Fastformer additive attention, MI355X (round 7):
//   - gemm_k staging rewritten to __builtin_amdgcn_global_load_lds (16B/lane,
//     linear LDS) -- m97 structure; epilogue C-bounce keeps padded stride via
//     a shared-memory union overlay.
//   - QK tile widened to 128x128 (NCT=8): 2x arithmetic intensity, grid 512.
//   - qs/ks row-sums fused into the QK epilogue (qsks kernel removed).
//   - stage_soft: log2e*SCALE folded into rowscale/bias -> single fma + v_exp_f32.
//   - T1 bijective XCD swizzle on gemm block ids (nwg % 8 == 0).
// Pipeline: conv -> QK(+qsks) -> stage1 -> stage2 -> VU -> OUT   (5 launches)

#define SCL 0.125f
#define SCL2 0.1803368801f   /* 0.125 * log2(e) */
typedef unsigned short u16;
typedef __attribute__((ext_vector_type(8))) short short8;   // 8 bf16 = 4 VGPR
typedef __attribute__((ext_vector_type(4))) float f32x4;

#define MFMA16(a, b, c) __builtin_amdgcn_mfma_f32_16x16x32_bf16((a), (b), (c), 0, 0, 0)

__device__ __forceinline__ float bf2f(u16 u) {
    union { unsigned int i; float f; } v; v.i = ((unsigned int)u) << 16; return v.f;
}
__device__ __forceinline__ u16 f2bf(float f) {
    union { float f; unsigned int i; } v; v.f = f;
    unsigned int x = v.i;
    return (u16)((x + 0x7FFFu + ((x >> 16) & 1u)) >> 16);
}

// async global->LDS, 16B per lane; LDS dest = wave-uniform base + lane*16
__device__ __forceinline__ void gload16(const u16* g, u16* l) {
    __builtin_amdgcn_global_load_lds(
        (__attribute__((address_space(1))) void*)(void*)g,
        (__attribute__((address_space(3))) void*)l, 16, 0, 0);
}

// ---------------------------------------------------------------------------
// f32 -> bf16: w_qkv | w_out | wq | wk | x   (contiguous ws block)
// ---------------------------------------------------------------------------
__global__ __launch_bounds__(256) void conv_kernel(
    const float* __restrict__ w_qkv, const float* __restrict__ w_out,
    const float* __restrict__ wq, const float* __restrict__ wk,
    const float* __restrict__ x, u16* __restrict__ wsb)
{
    const int idx = (blockIdx.x * 256 + threadIdx.x) * 4;
    const float* src; int off;
    if      (idx < 786432)  { src = w_qkv; off = idx; }
    else if (idx < 1048576) { src = w_out; off = idx - 786432; }
    else if (idx < 1114112) { src = wq;    off = idx - 1048576; }
    else if (idx < 1179648) { src = wk;    off = idx - 1114112; }
    else                    { src = x;     off = idx - 1179648; }
    float4 v = *(const float4*)(src + off);
    ushort4 o; o.x = f2bf(v.x); o.y = f2bf(v.y); o.z = f2bf(v.z); o.w = f2bf(v.w);
    *(ushort4*)(wsb + idx) = o;
}

// ---------------------------------------------------------------------------
// MFMA GEMM: tile 128M x (NCT*16)N, BK=64, K=512, 256 thr (4 waves, each
// 32 rows x NCT*16 cols). Staging via global_load_lds (linear LDS).
// Modes: QK (+b_qkv -> bf16 qkws, fused qs/ks row-sums), VU ((+bv)*kg ->
// qkws col+512), OUT (+b_out+qo -> f32 out). QK/VU bounce C through the
// padded half of the LDS union (conflict-free, coalesced stores).
// ---------------------------------------------------------------------------
#define MQK 0
#define MVU 1
#define MOUT 2

template <int MODE, int NCT>
__global__ __launch_bounds__(256) void gemm_k(
    const u16* __restrict__ Ab, int lda, int acol,
    const u16* __restrict__ Wb, const float* __restrict__ bias,
    const float* __restrict__ kg, const u16* __restrict__ qkws_ro,
    u16* __restrict__ qkws, float* __restrict__ outp,
    float* __restrict__ qsout, float* __restrict__ ksout)
{
    constexpr int BN = NCT * 16;        // tile N
    constexpr int CST = BN + 8;         // padded bounce stride (u16)
    __shared__ union SM {
        struct { u16 A[128 * 64]; u16 B[BN * 64]; } s;
        u16 C[128 * CST];
    } sm;

    const int t = threadIdx.x;
    const int w = t >> 6, lane = t & 63, s = lane & 15, quad = lane >> 4;

    // T1: bijective XCD swizzle (nwg % 8 == 0). Each XCD gets 8 consecutive
    // row-panels x all col-blocks -> ~2MB working set per XCD L2.
    const int nwgy = gridDim.y;
    const int nwg = gridDim.x * nwgy;
    const int flat = blockIdx.y * gridDim.x + blockIdx.x;
    const int swz = (flat & 7) * (nwg >> 3) + (flat >> 3);
    const int by = swz % nwgy, bx = swz / nwgy;
    const int bm = bx * 128, jn0 = by * BN;

    const int r8 = lane >> 3, c8 = (lane & 7) << 3;   // 8 rows x 8 chunks(16B)

    f32x4 acc[2][NCT];
#pragma unroll
    for (int i = 0; i < 2; ++i)
#pragma unroll
        for (int j = 0; j < NCT; ++j) acc[i][j] = (f32x4){0.f, 0.f, 0.f, 0.f};

    // per-wave staging bases: A rows [w*32, w*32+32), B rows [w*NCT*4, ...)
    const u16* ga = Ab + (size_t)(bm + w * 32 + r8) * lda + acol + c8;
    const u16* gb = Wb + (size_t)(jn0 + w * (NCT * 4) + r8) * 512 + c8;
    u16* la = &sm.s.A[(w * 32) * 64];
    u16* lb = &sm.s.B[(w * (NCT * 4)) * 64];

    for (int kt = 0; kt < 512; kt += 64) {
        __syncthreads();
#pragma unroll
        for (int j = 0; j < 4; ++j)
            gload16(ga + (size_t)j * 8 * lda + kt, la + j * 8 * 64);
#pragma unroll
        for (int j = 0; j < NCT / 2; ++j)
            gload16(gb + (size_t)j * 8 * 512 + kt, lb + j * 8 * 64);
        __syncthreads();   // drains vmcnt before barrier (global_load_lds done)
#pragma unroll
        for (int kk = 0; kk < 2; ++kk) {
            short8 a0 = *(const short8*)&sm.s.A[(w * 32 + s) * 64 + kk * 32 + quad * 8];
            short8 a1 = *(const short8*)&sm.s.A[(w * 32 + 16 + s) * 64 + kk * 32 + quad * 8];
#pragma unroll
            for (int ct = 0; ct < NCT; ++ct) {
                short8 bf = *(const short8*)&sm.s.B[(ct * 16 + s) * 64 + kk * 32 + quad * 8];
                acc[0][ct] = MFMA16(a0, bf, acc[0][ct]);
                acc[1][ct] = MFMA16(a1, bf, acc[1][ct]);
            }
        }
    }

    if constexpr (MODE == MOUT) {
#pragma unroll
        for (int mt = 0; mt < 2; ++mt)
#pragma unroll
            for (int ct = 0; ct < NCT; ++ct) {
                const int jn = jn0 + ct * 16 + s;
#pragma unroll
                for (int r = 0; r < 4; ++r) {
                    const int row = bm + w * 32 + mt * 16 + quad * 4 + r;
                    outp[(size_t)row * 512 + jn] =
                        acc[mt][ct][r] + bias[jn] + bf2f(qkws_ro[(size_t)row * 1024 + jn]);
                }
            }
    } else {
        float rsum[2][NCT / 4][4];
        if constexpr (MODE == MQK) {
#pragma unroll
            for (int mt = 0; mt < 2; ++mt)
#pragma unroll
                for (int hg = 0; hg < NCT / 4; ++hg)
#pragma unroll
                    for (int r = 0; r < 4; ++r) rsum[mt][hg][r] = 0.f;
        }
        __syncthreads();   // all LDS reads of s.A/s.B complete -> safe to overlay C
#pragma unroll
        for (int mt = 0; mt < 2; ++mt)
#pragma unroll
            for (int ct = 0; ct < NCT; ++ct) {
                const int jn = jn0 + ct * 16 + s;
                const float bj = bias[jn];
#pragma unroll
                for (int r = 0; r < 4; ++r) {
                    const int rowl = w * 32 + mt * 16 + quad * 4 + r;
                    float v = acc[mt][ct][r] + bj;
                    if constexpr (MODE == MVU) {
                        const int row = bm + rowl;
                        v *= kg[(((row >> 10) * 8 + (jn >> 6)) << 10) | (row & 1023)];
                    }
                    if constexpr (MODE == MQK) rsum[mt][ct >> 2][r] += v;
                    sm.C[rowl * CST + ct * 16 + s] = f2bf(v);
                }
            }
        if constexpr (MODE == MQK) {
            // fused qs/ks: per-row sum over each 64-col head group
#pragma unroll
            for (int mt = 0; mt < 2; ++mt)
#pragma unroll
                for (int hg = 0; hg < NCT / 4; ++hg)
#pragma unroll
                    for (int r = 0; r < 4; ++r) {
                        float S = rsum[mt][hg][r];
                        S += __shfl_xor(S, 1);
                        S += __shfl_xor(S, 2);
                        S += __shfl_xor(S, 4);
                        S += __shfl_xor(S, 8);
                        if (s == 0) {
                            const int row = bm + w * 32 + mt * 16 + quad * 4 + r;
                            const int jj = jn0 + hg * 64;
                            float* dst = (jj < 512) ? qsout : ksout;
                            dst[((((row >> 10) << 3) | ((jj >> 6) & 7)) << 10) | (row & 1023)] = S;
                        }
                    }
        }
        __syncthreads();
        const int row = t >> 1, ch = (t & 1) * (NCT * 8);
        u16* dp = qkws + (size_t)(bm + row) * 1024 + (MODE == MVU ? 512 : 0) + jn0 + ch;
#pragma unroll
        for (int i = 0; i < NCT; ++i)
            *(uint4*)(dp + i * 8) = *(const uint4*)&sm.C[row * CST + ch + i * 8];
    }
}

// ---------------------------------------------------------------------------
// Softmax stage, barrier-free hot loop. Block: 64 n-rows x one (b,h); wave w
// covers m in [w*256, w*256+256). log2e*SCL folded into rsS/bm2 so the inner
// element is one fma + one v_exp_f32.
//   stage1: qcol0=0,   rowscale=null, wv=qs
//   stage2: qcol0=512, rowscale=qg,   wv=qg*ks
// ---------------------------------------------------------------------------
__global__ __launch_bounds__(256) void stage_soft(
    const u16* __restrict__ qkws, int qcol0,
    const u16* __restrict__ wmb, const float* __restrict__ biasv,
    const float* __restrict__ rowscale,
    const float* __restrict__ wv1, const float* __restrict__ wv2,
    float* __restrict__ outg)
{
    __shared__ float zr[4][64], wr[4][64];
    const int t = threadIdx.x;
    const int w = t >> 6, lane = t & 63, s = lane & 15, quad = lane >> 4;
    const int n0 = blockIdx.x * 64;
    const int bh = blockIdx.y, b = bh >> 3, h = bh & 7;

    short8 qa[4][2];
#pragma unroll
    for (int nt = 0; nt < 4; ++nt)
#pragma unroll
        for (int kk = 0; kk < 2; ++kk)
            qa[nt][kk] = *(const short8*)&qkws[
                (size_t)((b << 10) + n0 + nt * 16 + s) * 1024 + qcol0 + (h << 6) + kk * 32 + quad * 8];

    float rsS[4][4];
#pragma unroll
    for (int nt = 0; nt < 4; ++nt)
#pragma unroll
        for (int r = 0; r < 4; ++r)
            rsS[nt][r] = (rowscale ? rowscale[(bh << 10) + n0 + nt * 16 + quad * 4 + r] : 1.0f) * SCL2;

    float z[4][4] = {}, wa[4][4] = {};

    for (int mi = 0; mi < 16; ++mi) {
        const int mt = w * 256 + mi * 16;
        const u16* bp = wmb + (size_t)(mt + s) * 64 + quad * 8;
        short8 bf0 = *(const short8*)bp;
        short8 bf1 = *(const short8*)(bp + 32);
        const float bm2 = biasv[mt + s] * SCL2;
        float wv = wv1[(bh << 10) + mt + s];
        if (wv2) wv *= wv2[(bh << 10) + mt + s];
#pragma unroll
        for (int nt = 0; nt < 4; ++nt) {
            f32x4 a = (f32x4){0.f, 0.f, 0.f, 0.f};
            a = MFMA16(qa[nt][0], bf0, a);
            a = MFMA16(qa[nt][1], bf1, a);
#pragma unroll
            for (int r = 0; r < 4; ++r) {
                const float e = __builtin_amdgcn_exp2f(rsS[nt][r] * a[r] + bm2);
                z[nt][r] += e;
                wa[nt][r] += e * wv;
            }
        }
    }

    // reduce over the 16 m-lanes of each quad, then across waves via LDS
#pragma unroll
    for (int nt = 0; nt < 4; ++nt)
#pragma unroll
        for (int r = 0; r < 4; ++r) {
            float Z = z[nt][r], W = wa[nt][r];
            for (int off = 1; off < 16; off <<= 1) {
                Z += __shfl_xor(Z, off);
                W += __shfl_xor(W, off);
            }
            if (s == 0) {
                zr[w][nt * 16 + quad * 4 + r] = Z;
                wr[w][nt * 16 + quad * 4 + r] = W;
            }
        }
    __syncthreads();
    if (t < 64) {
        float Z = zr[0][t] + zr[1][t] + zr[2][t] + zr[3][t];
        float W = wr[0][t] + wr[1][t] + wr[2][t] + wr[3][t];
        outg[(bh << 10) + n0 + t] = W / Z;
    }
}

// ---------------------------------------------------------------------------
extern "C" void kernel_launch(void* const* d_in, const int* in_sizes, int n_in,
                              void* d_out, int out_size, void* d_ws, size_t ws_size,
                              hipStream_t stream)
{
    const float* x     = (const float*)d_in[0];
    const float* w_qkv = (const float*)d_in[1];
    const float* b_qkv = (const float*)d_in[2];
    const float* wq    = (const float*)d_in[3];
    const float* bq    = (const float*)d_in[4];
    const float* wk    = (const float*)d_in[5];
    const float* bk    = (const float*)d_in[6];
    const float* w_out = (const float*)d_in[7];
    const float* b_out = (const float*)d_in[8];
    float* out = (float*)d_out;

    // ws: qs|ks|qg|kg (65536 f32) | bf16: wqkv|wout|wq|wk|x | qk ws bf16
    float* qs = (float*)d_ws;
    float* ks = qs + 65536;
    float* qg = ks + 65536;
    float* kg = qg + 65536;
    u16* wsb   = (u16*)(kg + 65536);
    u16* wqkvb = wsb;
    u16* woutb = wqkvb + 786432;
    u16* wqb   = woutb + 262144;
    u16* wkb   = wqb + 65536;
    u16* xb    = wkb + 65536;
    u16* qkws  = xb + 4194304;

    // 5,373,952 f32 -> bf16 (weights + x), 4 elems/thread
    conv_kernel<<<5248, 256, 0, stream>>>(w_qkv, w_out, wq, wk, x, wsb);
    // QK: qk = x @ w_qkv[0:1024]^T + b_qkv  (128x128 tile) + fused qs/ks
    gemm_k<MQK, 8><<<dim3(64, 8), 256, 0, stream>>>(
        xb, 512, 0, wqkvb, b_qkv, nullptr, nullptr, qkws, nullptr, qs, ks);
    // stage 1 -> qg
    stage_soft<<<dim3(16, 64), 256, 0, stream>>>(
        qkws, 0, wqb, bq, nullptr, qs, nullptr, qg);
    // stage 2 -> kg
    stage_soft<<<dim3(16, 64), 256, 0, stream>>>(
        qkws, 512, wkb, bk, qg, qg, ks, kg);
    // VU: U = (x @ w_qkv[1024:]^T + bv) * kg  (into k-half of qk ws)
    gemm_k<MVU, 4><<<dim3(64, 8), 256, 0, stream>>>(
        xb, 512, 0, wqkvb + (size_t)1024 * 512, b_qkv + 1024, kg, nullptr, qkws, nullptr,
        nullptr, nullptr);
    // OUT: out = U @ w_out^T + b_out + qo
    gemm_k<MOUT, 4><<<dim3(64, 8), 256, 0, stream>>>(
        qkws, 1024, 512, woutb, b_out, nullptr, qkws, nullptr, out, nullptr, nullptr);
}

// Round 2
// 189.221 us; speedup vs baseline: 1.0450x; 1.0450x over previous
//
#include <hip/hip_runtime.h>

// Fastformer additive attention, MI355X (round 8):
//   - round-7 structure (global_load_lds staging, 128x128 QK tile, fused
//     qs/ks, exp2 constant-fold, XCD swizzle) PLUS the rule-#21 fix:
//     linear LDS dest + inverse-swizzled GLOBAL source + XOR-swizzled
//     fragment reads. Kills the 2x bank-conflict penalty round 7 introduced
//     (128B-stride rows -> 4/8 granules; now even 8/8).
// Pipeline: conv -> QK(+qsks) -> stage1 -> stage2 -> VU -> OUT   (6 launches)

#define SCL 0.125f
#define SCL2 0.1803368801f   /* 0.125 * log2(e) */
typedef unsigned short u16;
typedef __attribute__((ext_vector_type(8))) short short8;   // 8 bf16 = 4 VGPR
typedef __attribute__((ext_vector_type(4))) float f32x4;

#define MFMA16(a, b, c) __builtin_amdgcn_mfma_f32_16x16x32_bf16((a), (b), (c), 0, 0, 0)

__device__ __forceinline__ float bf2f(u16 u) {
    union { unsigned int i; float f; } v; v.i = ((unsigned int)u) << 16; return v.f;
}
__device__ __forceinline__ u16 f2bf(float f) {
    union { float f; unsigned int i; } v; v.f = f;
    unsigned int x = v.i;
    return (u16)((x + 0x7FFFu + ((x >> 16) & 1u)) >> 16);
}

// async global->LDS, 16B per lane; LDS dest = wave-uniform base + lane*16
__device__ __forceinline__ void gload16(const u16* g, u16* l) {
    __builtin_amdgcn_global_load_lds(
        (__attribute__((address_space(1))) void*)(void*)g,
        (__attribute__((address_space(3))) void*)l, 16, 0, 0);
}

// ---------------------------------------------------------------------------
// f32 -> bf16: w_qkv | w_out | wq | wk | x   (contiguous ws block)
// ---------------------------------------------------------------------------
__global__ __launch_bounds__(256) void conv_kernel(
    const float* __restrict__ w_qkv, const float* __restrict__ w_out,
    const float* __restrict__ wq, const float* __restrict__ wk,
    const float* __restrict__ x, u16* __restrict__ wsb)
{
    const int idx = (blockIdx.x * 256 + threadIdx.x) * 4;
    const float* src; int off;
    if      (idx < 786432)  { src = w_qkv; off = idx; }
    else if (idx < 1048576) { src = w_out; off = idx - 786432; }
    else if (idx < 1114112) { src = wq;    off = idx - 1048576; }
    else if (idx < 1179648) { src = wk;    off = idx - 1114112; }
    else                    { src = x;     off = idx - 1179648; }
    float4 v = *(const float4*)(src + off);
    ushort4 o; o.x = f2bf(v.x); o.y = f2bf(v.y); o.z = f2bf(v.z); o.w = f2bf(v.w);
    *(ushort4*)(wsb + idx) = o;
}

// ---------------------------------------------------------------------------
// MFMA GEMM: tile 128M x (NCT*16)N, BK=64, K=512, 256 thr (4 waves, each
// 32 rows x NCT*16 cols). Staging via global_load_lds, linear LDS dest,
// source chunk pre-swizzled with (lane&7)^(lane>>3); fragment reads XOR
// their 16B-chunk index with (row&7) -> conflict-free (8/8 granules).
// Modes: QK (+b_qkv -> bf16 qkws, fused qs/ks row-sums), VU ((+bv)*kg ->
// qkws col+512), OUT (+b_out+qo -> f32 out). QK/VU bounce C through the
// padded half of the LDS union (conflict-free, coalesced stores).
// ---------------------------------------------------------------------------
#define MQK 0
#define MVU 1
#define MOUT 2

template <int MODE, int NCT>
__global__ __launch_bounds__(256) void gemm_k(
    const u16* __restrict__ Ab, int lda, int acol,
    const u16* __restrict__ Wb, const float* __restrict__ bias,
    const float* __restrict__ kg, const u16* __restrict__ qkws_ro,
    u16* __restrict__ qkws, float* __restrict__ outp,
    float* __restrict__ qsout, float* __restrict__ ksout)
{
    constexpr int BN = NCT * 16;        // tile N
    constexpr int CST = BN + 8;         // padded bounce stride (u16)
    __shared__ union SM {
        struct { u16 A[128 * 64]; u16 B[BN * 64]; } s;
        u16 C[128 * CST];
    } sm;

    const int t = threadIdx.x;
    const int w = t >> 6, lane = t & 63, s = lane & 15, quad = lane >> 4;
    const int sx = lane & 7;            // row&7 of every fragment row this lane reads

    // T1: bijective XCD swizzle (nwg % 8 == 0). Each XCD gets consecutive
    // row-panels x all col-blocks -> L2-resident working set per XCD.
    const int nwgy = gridDim.y;
    const int nwg = gridDim.x * nwgy;
    const int flat = blockIdx.y * gridDim.x + blockIdx.x;
    const int swz = (flat & 7) * (nwg >> 3) + (flat >> 3);
    const int by = swz % nwgy, bx = swz / nwgy;
    const int bm = bx * 128, jn0 = by * BN;

    const int r8 = lane >> 3;                         // staged row within 8-row group
    const int c8x = ((lane & 7) ^ r8) << 3;           // swizzled source chunk (u16)

    f32x4 acc[2][NCT];
#pragma unroll
    for (int i = 0; i < 2; ++i)
#pragma unroll
        for (int j = 0; j < NCT; ++j) acc[i][j] = (f32x4){0.f, 0.f, 0.f, 0.f};

    // per-wave staging bases: A rows [w*32, w*32+32), B rows [w*NCT*4, ...)
    const u16* ga = Ab + (size_t)(bm + w * 32 + r8) * lda + acol + c8x;
    const u16* gb = Wb + (size_t)(jn0 + w * (NCT * 4) + r8) * 512 + c8x;
    u16* la = &sm.s.A[(w * 32) * 64];
    u16* lb = &sm.s.B[(w * (NCT * 4)) * 64];

    for (int kt = 0; kt < 512; kt += 64) {
        __syncthreads();
#pragma unroll
        for (int j = 0; j < 4; ++j)
            gload16(ga + (size_t)j * 8 * lda + kt, la + j * 8 * 64);
#pragma unroll
        for (int j = 0; j < NCT / 2; ++j)
            gload16(gb + (size_t)j * 8 * 512 + kt, lb + j * 8 * 64);
        __syncthreads();   // drains vmcnt before barrier (global_load_lds done)
#pragma unroll
        for (int kk = 0; kk < 2; ++kk) {
            const int ca = ((kk * 4 + quad) ^ sx) << 3;   // swizzled read chunk (u16)
            short8 a0 = *(const short8*)&sm.s.A[(w * 32 + s) * 64 + ca];
            short8 a1 = *(const short8*)&sm.s.A[(w * 32 + 16 + s) * 64 + ca];
#pragma unroll
            for (int ct = 0; ct < NCT; ++ct) {
                short8 bf = *(const short8*)&sm.s.B[(ct * 16 + s) * 64 + ca];
                acc[0][ct] = MFMA16(a0, bf, acc[0][ct]);
                acc[1][ct] = MFMA16(a1, bf, acc[1][ct]);
            }
        }
    }

    if constexpr (MODE == MOUT) {
#pragma unroll
        for (int mt = 0; mt < 2; ++mt)
#pragma unroll
            for (int ct = 0; ct < NCT; ++ct) {
                const int jn = jn0 + ct * 16 + s;
#pragma unroll
                for (int r = 0; r < 4; ++r) {
                    const int row = bm + w * 32 + mt * 16 + quad * 4 + r;
                    outp[(size_t)row * 512 + jn] =
                        acc[mt][ct][r] + bias[jn] + bf2f(qkws_ro[(size_t)row * 1024 + jn]);
                }
            }
    } else {
        float rsum[2][NCT / 4][4];
        if constexpr (MODE == MQK) {
#pragma unroll
            for (int mt = 0; mt < 2; ++mt)
#pragma unroll
                for (int hg = 0; hg < NCT / 4; ++hg)
#pragma unroll
                    for (int r = 0; r < 4; ++r) rsum[mt][hg][r] = 0.f;
        }
        __syncthreads();   // all LDS reads of s.A/s.B complete -> safe to overlay C
#pragma unroll
        for (int mt = 0; mt < 2; ++mt)
#pragma unroll
            for (int ct = 0; ct < NCT; ++ct) {
                const int jn = jn0 + ct * 16 + s;
                const float bj = bias[jn];
#pragma unroll
                for (int r = 0; r < 4; ++r) {
                    const int rowl = w * 32 + mt * 16 + quad * 4 + r;
                    float v = acc[mt][ct][r] + bj;
                    if constexpr (MODE == MVU) {
                        const int row = bm + rowl;
                        v *= kg[(((row >> 10) * 8 + (jn >> 6)) << 10) | (row & 1023)];
                    }
                    if constexpr (MODE == MQK) rsum[mt][ct >> 2][r] += v;
                    sm.C[rowl * CST + ct * 16 + s] = f2bf(v);
                }
            }
        if constexpr (MODE == MQK) {
            // fused qs/ks: per-row sum over each 64-col head group
#pragma unroll
            for (int mt = 0; mt < 2; ++mt)
#pragma unroll
                for (int hg = 0; hg < NCT / 4; ++hg)
#pragma unroll
                    for (int r = 0; r < 4; ++r) {
                        float S = rsum[mt][hg][r];
                        S += __shfl_xor(S, 1);
                        S += __shfl_xor(S, 2);
                        S += __shfl_xor(S, 4);
                        S += __shfl_xor(S, 8);
                        if (s == 0) {
                            const int row = bm + w * 32 + mt * 16 + quad * 4 + r;
                            const int jj = jn0 + hg * 64;
                            float* dst = (jj < 512) ? qsout : ksout;
                            dst[((((row >> 10) << 3) | ((jj >> 6) & 7)) << 10) | (row & 1023)] = S;
                        }
                    }
        }
        __syncthreads();
        const int row = t >> 1, ch = (t & 1) * (NCT * 8);
        u16* dp = qkws + (size_t)(bm + row) * 1024 + (MODE == MVU ? 512 : 0) + jn0 + ch;
#pragma unroll
        for (int i = 0; i < NCT; ++i)
            *(uint4*)(dp + i * 8) = *(const uint4*)&sm.C[row * CST + ch + i * 8];
    }
}

// ---------------------------------------------------------------------------
// Softmax stage, barrier-free hot loop. Block: 64 n-rows x one (b,h); wave w
// covers m in [w*256, w*256+256). log2e*SCL folded into rsS/bm2 so the inner
// element is one fma + one v_exp_f32.
//   stage1: qcol0=0,   rowscale=null, wv=qs
//   stage2: qcol0=512, rowscale=qg,   wv=qg*ks
// ---------------------------------------------------------------------------
__global__ __launch_bounds__(256) void stage_soft(
    const u16* __restrict__ qkws, int qcol0,
    const u16* __restrict__ wmb, const float* __restrict__ biasv,
    const float* __restrict__ rowscale,
    const float* __restrict__ wv1, const float* __restrict__ wv2,
    float* __restrict__ outg)
{
    __shared__ float zr[4][64], wr[4][64];
    const int t = threadIdx.x;
    const int w = t >> 6, lane = t & 63, s = lane & 15, quad = lane >> 4;
    const int n0 = blockIdx.x * 64;
    const int bh = blockIdx.y, b = bh >> 3, h = bh & 7;

    short8 qa[4][2];
#pragma unroll
    for (int nt = 0; nt < 4; ++nt)
#pragma unroll
        for (int kk = 0; kk < 2; ++kk)
            qa[nt][kk] = *(const short8*)&qkws[
                (size_t)((b << 10) + n0 + nt * 16 + s) * 1024 + qcol0 + (h << 6) + kk * 32 + quad * 8];

    float rsS[4][4];
#pragma unroll
    for (int nt = 0; nt < 4; ++nt)
#pragma unroll
        for (int r = 0; r < 4; ++r)
            rsS[nt][r] = (rowscale ? rowscale[(bh << 10) + n0 + nt * 16 + quad * 4 + r] : 1.0f) * SCL2;

    float z[4][4] = {}, wa[4][4] = {};

    for (int mi = 0; mi < 16; ++mi) {
        const int mt = w * 256 + mi * 16;
        const u16* bp = wmb + (size_t)(mt + s) * 64 + quad * 8;
        short8 bf0 = *(const short8*)bp;
        short8 bf1 = *(const short8*)(bp + 32);
        const float bm2 = biasv[mt + s] * SCL2;
        float wv = wv1[(bh << 10) + mt + s];
        if (wv2) wv *= wv2[(bh << 10) + mt + s];
#pragma unroll
        for (int nt = 0; nt < 4; ++nt) {
            f32x4 a = (f32x4){0.f, 0.f, 0.f, 0.f};
            a = MFMA16(qa[nt][0], bf0, a);
            a = MFMA16(qa[nt][1], bf1, a);
#pragma unroll
            for (int r = 0; r < 4; ++r) {
                const float e = __builtin_amdgcn_exp2f(rsS[nt][r] * a[r] + bm2);
                z[nt][r] += e;
                wa[nt][r] += e * wv;
            }
        }
    }

    // reduce over the 16 m-lanes of each quad, then across waves via LDS
#pragma unroll
    for (int nt = 0; nt < 4; ++nt)
#pragma unroll
        for (int r = 0; r < 4; ++r) {
            float Z = z[nt][r], W = wa[nt][r];
            for (int off = 1; off < 16; off <<= 1) {
                Z += __shfl_xor(Z, off);
                W += __shfl_xor(W, off);
            }
            if (s == 0) {
                zr[w][nt * 16 + quad * 4 + r] = Z;
                wr[w][nt * 16 + quad * 4 + r] = W;
            }
        }
    __syncthreads();
    if (t < 64) {
        float Z = zr[0][t] + zr[1][t] + zr[2][t] + zr[3][t];
        float W = wr[0][t] + wr[1][t] + wr[2][t] + wr[3][t];
        outg[(bh << 10) + n0 + t] = W / Z;
    }
}

// ---------------------------------------------------------------------------
extern "C" void kernel_launch(void* const* d_in, const int* in_sizes, int n_in,
                              void* d_out, int out_size, void* d_ws, size_t ws_size,
                              hipStream_t stream)
{
    const float* x     = (const float*)d_in[0];
    const float* w_qkv = (const float*)d_in[1];
    const float* b_qkv = (const float*)d_in[2];
    const float* wq    = (const float*)d_in[3];
    const float* bq    = (const float*)d_in[4];
    const float* wk    = (const float*)d_in[5];
    const float* bk    = (const float*)d_in[6];
    const float* w_out = (const float*)d_in[7];
    const float* b_out = (const float*)d_in[8];
    float* out = (float*)d_out;

    // ws: qs|ks|qg|kg (65536 f32) | bf16: wqkv|wout|wq|wk|x | qk ws bf16
    float* qs = (float*)d_ws;
    float* ks = qs + 65536;
    float* qg = ks + 65536;
    float* kg = qg + 65536;
    u16* wsb   = (u16*)(kg + 65536);
    u16* wqkvb = wsb;
    u16* woutb = wqkvb + 786432;
    u16* wqb   = woutb + 262144;
    u16* wkb   = wqb + 65536;
    u16* xb    = wkb + 65536;
    u16* qkws  = xb + 4194304;

    // 5,373,952 f32 -> bf16 (weights + x), 4 elems/thread
    conv_kernel<<<5248, 256, 0, stream>>>(w_qkv, w_out, wq, wk, x, wsb);
    // QK: qk = x @ w_qkv[0:1024]^T + b_qkv  (128x128 tile) + fused qs/ks
    gemm_k<MQK, 8><<<dim3(64, 8), 256, 0, stream>>>(
        xb, 512, 0, wqkvb, b_qkv, nullptr, nullptr, qkws, nullptr, qs, ks);
    // stage 1 -> qg
    stage_soft<<<dim3(16, 64), 256, 0, stream>>>(
        qkws, 0, wqb, bq, nullptr, qs, nullptr, qg);
    // stage 2 -> kg
    stage_soft<<<dim3(16, 64), 256, 0, stream>>>(
        qkws, 512, wkb, bk, qg, qg, ks, kg);
    // VU: U = (x @ w_qkv[1024:]^T + bv) * kg  (into k-half of qk ws)
    gemm_k<MVU, 4><<<dim3(64, 8), 256, 0, stream>>>(
        xb, 512, 0, wqkvb + (size_t)1024 * 512, b_qkv + 1024, kg, nullptr, qkws, nullptr,
        nullptr, nullptr);
    // OUT: out = U @ w_out^T + b_out + qo
    gemm_k<MOUT, 4><<<dim3(64, 8), 256, 0, stream>>>(
        qkws, 1024, 512, woutb, b_out, nullptr, qkws, nullptr, out, nullptr, nullptr);
}

// Round 3
// 183.100 us; speedup vs baseline: 1.0800x; 1.0334x over previous
//
#include <hip/hip_runtime.h>

// Fastformer additive attention, MI355X (round 9):
//   - round-8 structure (gload_lds + source/read XOR swizzle, fused qs/ks,
//     exp2 fold, XCD swizzle) PLUS T3-minimum K-loop pipeline:
//     LDS double-buffer, stage(next) issued BEFORE compute(cur), single
//     __syncthreads per K-step (drain lands after compute has hidden the
//     load latency). Buffer parity chosen so the final compute reads buf0;
//     the padded C-bounce overlays buf1 only (no WAR hazard).
// Pipeline: conv -> QK(+qsks) -> stage1 -> stage2 -> VU -> OUT   (6 launches)

#define SCL 0.125f
#define SCL2 0.1803368801f   /* 0.125 * log2(e) */
typedef unsigned short u16;
typedef __attribute__((ext_vector_type(8))) short short8;   // 8 bf16 = 4 VGPR
typedef __attribute__((ext_vector_type(4))) float f32x4;

#define MFMA16(a, b, c) __builtin_amdgcn_mfma_f32_16x16x32_bf16((a), (b), (c), 0, 0, 0)

__device__ __forceinline__ float bf2f(u16 u) {
    union { unsigned int i; float f; } v; v.i = ((unsigned int)u) << 16; return v.f;
}
__device__ __forceinline__ u16 f2bf(float f) {
    union { float f; unsigned int i; } v; v.f = f;
    unsigned int x = v.i;
    return (u16)((x + 0x7FFFu + ((x >> 16) & 1u)) >> 16);
}

// async global->LDS, 16B per lane; LDS dest = wave-uniform base + lane*16
__device__ __forceinline__ void gload16(const u16* g, u16* l) {
    __builtin_amdgcn_global_load_lds(
        (__attribute__((address_space(1))) void*)(void*)g,
        (__attribute__((address_space(3))) void*)l, 16, 0, 0);
}

// ---------------------------------------------------------------------------
// f32 -> bf16: w_qkv | w_out | wq | wk | x   (contiguous ws block)
// ---------------------------------------------------------------------------
__global__ __launch_bounds__(256) void conv_kernel(
    const float* __restrict__ w_qkv, const float* __restrict__ w_out,
    const float* __restrict__ wq, const float* __restrict__ wk,
    const float* __restrict__ x, u16* __restrict__ wsb)
{
    const int idx = (blockIdx.x * 256 + threadIdx.x) * 4;
    const float* src; int off;
    if      (idx < 786432)  { src = w_qkv; off = idx; }
    else if (idx < 1048576) { src = w_out; off = idx - 786432; }
    else if (idx < 1114112) { src = wq;    off = idx - 1048576; }
    else if (idx < 1179648) { src = wk;    off = idx - 1114112; }
    else                    { src = x;     off = idx - 1179648; }
    float4 v = *(const float4*)(src + off);
    ushort4 o; o.x = f2bf(v.x); o.y = f2bf(v.y); o.z = f2bf(v.z); o.w = f2bf(v.w);
    *(ushort4*)(wsb + idx) = o;
}

// ---------------------------------------------------------------------------
// MFMA GEMM: tile 128M x (NCT*16)N, BK=64, K=512, 256 thr (4 waves).
// Double-buffered gload_lds staging (linear LDS dest, source chunk swizzled
// with (lane&7)^(lane>>3)); fragment reads XOR chunk idx with (row&7).
// K-loop: stage(next buf) -> sched_barrier -> compute(cur) -> syncthreads.
// Final compute reads buf0; C bounce (padded stride) overlays buf1.
// ---------------------------------------------------------------------------
#define MQK 0
#define MVU 1
#define MOUT 2

template <int MODE, int NCT>
__global__ __launch_bounds__(256) void gemm_k(
    const u16* __restrict__ Ab, int lda, int acol,
    const u16* __restrict__ Wb, const float* __restrict__ bias,
    const float* __restrict__ kg, const u16* __restrict__ qkws_ro,
    u16* __restrict__ qkws, float* __restrict__ outp,
    float* __restrict__ qsout, float* __restrict__ ksout)
{
    constexpr int BN = NCT * 16;            // tile N
    constexpr int CST = BN + 8;             // padded bounce stride (u16)
    constexpr int ASZ = 128 * 64;           // A elems per buffer
    constexpr int BSZ = BN * 64;            // B elems per buffer
    constexpr int HALF = ASZ + BSZ;         // one double-buffer half
    constexpr int CELEM = 128 * CST;
    constexpr int SMSZ = (2 * HALF > HALF + CELEM) ? 2 * HALF : HALF + CELEM;
    __shared__ u16 sm[SMSZ];
    u16* const Cb = sm + HALF;              // C bounce overlays buf1 only

    const int t = threadIdx.x;
    const int w = t >> 6, lane = t & 63, s = lane & 15, quad = lane >> 4;
    const int sx = lane & 7;                // row&7 of every fragment row read

    // T1: bijective XCD swizzle (nwg % 8 == 0)
    const int nwgy = gridDim.y;
    const int nwg = gridDim.x * nwgy;
    const int flat = blockIdx.y * gridDim.x + blockIdx.x;
    const int swz = (flat & 7) * (nwg >> 3) + (flat >> 3);
    const int by = swz % nwgy, bx = swz / nwgy;
    const int bm = bx * 128, jn0 = by * BN;

    const int r8 = lane >> 3;                       // staged row within 8-row group
    const int c8x = ((lane & 7) ^ r8) << 3;         // swizzled source chunk (u16)

    f32x4 acc[2][NCT];
#pragma unroll
    for (int i = 0; i < 2; ++i)
#pragma unroll
        for (int j = 0; j < NCT; ++j) acc[i][j] = (f32x4){0.f, 0.f, 0.f, 0.f};

    // per-wave staging bases: A rows [w*32, w*32+32), B rows [w*NCT*4, ...)
    const u16* ga = Ab + (size_t)(bm + w * 32 + r8) * lda + acol + c8x;
    const u16* gb = Wb + (size_t)(jn0 + w * (NCT * 4) + r8) * 512 + c8x;

    auto stage = [&](int buf, int kt) {
        u16* la = sm + buf * HALF + (w * 32) * 64;
        u16* lb = sm + buf * HALF + ASZ + (w * (NCT * 4)) * 64;
#pragma unroll
        for (int j = 0; j < 4; ++j)
            gload16(ga + (size_t)j * 8 * lda + kt, la + j * 8 * 64);
#pragma unroll
        for (int j = 0; j < NCT / 2; ++j)
            gload16(gb + (size_t)j * 8 * 512 + kt, lb + j * 8 * 64);
    };
    auto compute = [&](int buf) {
        const u16* Ab_ = sm + buf * HALF;
        const u16* Bb_ = Ab_ + ASZ;
#pragma unroll
        for (int kk = 0; kk < 2; ++kk) {
            const int ca = ((kk * 4 + quad) ^ sx) << 3;   // swizzled read chunk
            short8 a0 = *(const short8*)&Ab_[(w * 32 + s) * 64 + ca];
            short8 a1 = *(const short8*)&Ab_[(w * 32 + 16 + s) * 64 + ca];
#pragma unroll
            for (int ct = 0; ct < NCT; ++ct) {
                short8 bf = *(const short8*)&Bb_[(ct * 16 + s) * 64 + ca];
                acc[0][ct] = MFMA16(a0, bf, acc[0][ct]);
                acc[1][ct] = MFMA16(a1, bf, acc[1][ct]);
            }
        }
    };

    // Pipeline: prologue stages tile0 into buf1; computes alternate 1,0,1,...
    // 7 in-loop computes end on buf1, epilogue computes buf0 (tile 448).
    stage(1, 0);
    __syncthreads();
#pragma unroll
    for (int it = 0; it < 7; ++it) {
        const int cur = 1 - (it & 1);
        stage(1 - cur, 64 * (it + 1));            // issue next-tile loads
        __builtin_amdgcn_sched_barrier(0);        // pin issue-before-compute
        compute(cur);
        __syncthreads();                          // drains prefetch; guards WAR
    }
    compute(0);

    if constexpr (MODE == MOUT) {
#pragma unroll
        for (int mt = 0; mt < 2; ++mt)
#pragma unroll
            for (int ct = 0; ct < NCT; ++ct) {
                const int jn = jn0 + ct * 16 + s;
#pragma unroll
                for (int r = 0; r < 4; ++r) {
                    const int row = bm + w * 32 + mt * 16 + quad * 4 + r;
                    outp[(size_t)row * 512 + jn] =
                        acc[mt][ct][r] + bias[jn] + bf2f(qkws_ro[(size_t)row * 1024 + jn]);
                }
            }
    } else {
        float rsum[2][NCT / 4][4];
        if constexpr (MODE == MQK) {
#pragma unroll
            for (int mt = 0; mt < 2; ++mt)
#pragma unroll
                for (int hg = 0; hg < NCT / 4; ++hg)
#pragma unroll
                    for (int r = 0; r < 4; ++r) rsum[mt][hg][r] = 0.f;
        }
        __syncthreads();   // final-buf reads (buf0) done; C overlays buf1 anyway
#pragma unroll
        for (int mt = 0; mt < 2; ++mt)
#pragma unroll
            for (int ct = 0; ct < NCT; ++ct) {
                const int jn = jn0 + ct * 16 + s;
                const float bj = bias[jn];
#pragma unroll
                for (int r = 0; r < 4; ++r) {
                    const int rowl = w * 32 + mt * 16 + quad * 4 + r;
                    float v = acc[mt][ct][r] + bj;
                    if constexpr (MODE == MVU) {
                        const int row = bm + rowl;
                        v *= kg[(((row >> 10) * 8 + (jn >> 6)) << 10) | (row & 1023)];
                    }
                    if constexpr (MODE == MQK) rsum[mt][ct >> 2][r] += v;
                    Cb[rowl * CST + ct * 16 + s] = f2bf(v);
                }
            }
        if constexpr (MODE == MQK) {
            // fused qs/ks: per-row sum over each 64-col head group
#pragma unroll
            for (int mt = 0; mt < 2; ++mt)
#pragma unroll
                for (int hg = 0; hg < NCT / 4; ++hg)
#pragma unroll
                    for (int r = 0; r < 4; ++r) {
                        float S = rsum[mt][hg][r];
                        S += __shfl_xor(S, 1);
                        S += __shfl_xor(S, 2);
                        S += __shfl_xor(S, 4);
                        S += __shfl_xor(S, 8);
                        if (s == 0) {
                            const int row = bm + w * 32 + mt * 16 + quad * 4 + r;
                            const int jj = jn0 + hg * 64;
                            float* dst = (jj < 512) ? qsout : ksout;
                            dst[((((row >> 10) << 3) | ((jj >> 6) & 7)) << 10) | (row & 1023)] = S;
                        }
                    }
        }
        __syncthreads();
        const int row = t >> 1, ch = (t & 1) * (NCT * 8);
        u16* dp = qkws + (size_t)(bm + row) * 1024 + (MODE == MVU ? 512 : 0) + jn0 + ch;
#pragma unroll
        for (int i = 0; i < NCT; ++i)
            *(uint4*)(dp + i * 8) = *(const uint4*)&Cb[row * CST + ch + i * 8];
    }
}

// ---------------------------------------------------------------------------
// Softmax stage, barrier-free hot loop. Block: 64 n-rows x one (b,h); wave w
// covers m in [w*256, w*256+256). log2e*SCL folded into rsS/bm2 so the inner
// element is one fma + one v_exp_f32.
//   stage1: qcol0=0,   rowscale=null, wv=qs
//   stage2: qcol0=512, rowscale=qg,   wv=qg*ks
// ---------------------------------------------------------------------------
__global__ __launch_bounds__(256) void stage_soft(
    const u16* __restrict__ qkws, int qcol0,
    const u16* __restrict__ wmb, const float* __restrict__ biasv,
    const float* __restrict__ rowscale,
    const float* __restrict__ wv1, const float* __restrict__ wv2,
    float* __restrict__ outg)
{
    __shared__ float zr[4][64], wr[4][64];
    const int t = threadIdx.x;
    const int w = t >> 6, lane = t & 63, s = lane & 15, quad = lane >> 4;
    const int n0 = blockIdx.x * 64;
    const int bh = blockIdx.y, b = bh >> 3, h = bh & 7;

    short8 qa[4][2];
#pragma unroll
    for (int nt = 0; nt < 4; ++nt)
#pragma unroll
        for (int kk = 0; kk < 2; ++kk)
            qa[nt][kk] = *(const short8*)&qkws[
                (size_t)((b << 10) + n0 + nt * 16 + s) * 1024 + qcol0 + (h << 6) + kk * 32 + quad * 8];

    float rsS[4][4];
#pragma unroll
    for (int nt = 0; nt < 4; ++nt)
#pragma unroll
        for (int r = 0; r < 4; ++r)
            rsS[nt][r] = (rowscale ? rowscale[(bh << 10) + n0 + nt * 16 + quad * 4 + r] : 1.0f) * SCL2;

    float z[4][4] = {}, wa[4][4] = {};

    for (int mi = 0; mi < 16; ++mi) {
        const int mt = w * 256 + mi * 16;
        const u16* bp = wmb + (size_t)(mt + s) * 64 + quad * 8;
        short8 bf0 = *(const short8*)bp;
        short8 bf1 = *(const short8*)(bp + 32);
        const float bm2 = biasv[mt + s] * SCL2;
        float wv = wv1[(bh << 10) + mt + s];
        if (wv2) wv *= wv2[(bh << 10) + mt + s];
#pragma unroll
        for (int nt = 0; nt < 4; ++nt) {
            f32x4 a = (f32x4){0.f, 0.f, 0.f, 0.f};
            a = MFMA16(qa[nt][0], bf0, a);
            a = MFMA16(qa[nt][1], bf1, a);
#pragma unroll
            for (int r = 0; r < 4; ++r) {
                const float e = __builtin_amdgcn_exp2f(rsS[nt][r] * a[r] + bm2);
                z[nt][r] += e;
                wa[nt][r] += e * wv;
            }
        }
    }

    // reduce over the 16 m-lanes of each quad, then across waves via LDS
#pragma unroll
    for (int nt = 0; nt < 4; ++nt)
#pragma unroll
        for (int r = 0; r < 4; ++r) {
            float Z = z[nt][r], W = wa[nt][r];
            for (int off = 1; off < 16; off <<= 1) {
                Z += __shfl_xor(Z, off);
                W += __shfl_xor(W, off);
            }
            if (s == 0) {
                zr[w][nt * 16 + quad * 4 + r] = Z;
                wr[w][nt * 16 + quad * 4 + r] = W;
            }
        }
    __syncthreads();
    if (t < 64) {
        float Z = zr[0][t] + zr[1][t] + zr[2][t] + zr[3][t];
        float W = wr[0][t] + wr[1][t] + wr[2][t] + wr[3][t];
        outg[(bh << 10) + n0 + t] = W / Z;
    }
}

// ---------------------------------------------------------------------------
extern "C" void kernel_launch(void* const* d_in, const int* in_sizes, int n_in,
                              void* d_out, int out_size, void* d_ws, size_t ws_size,
                              hipStream_t stream)
{
    const float* x     = (const float*)d_in[0];
    const float* w_qkv = (const float*)d_in[1];
    const float* b_qkv = (const float*)d_in[2];
    const float* wq    = (const float*)d_in[3];
    const float* bq    = (const float*)d_in[4];
    const float* wk    = (const float*)d_in[5];
    const float* bk    = (const float*)d_in[6];
    const float* w_out = (const float*)d_in[7];
    const float* b_out = (const float*)d_in[8];
    float* out = (float*)d_out;

    // ws: qs|ks|qg|kg (65536 f32) | bf16: wqkv|wout|wq|wk|x | qk ws bf16
    float* qs = (float*)d_ws;
    float* ks = qs + 65536;
    float* qg = ks + 65536;
    float* kg = qg + 65536;
    u16* wsb   = (u16*)(kg + 65536);
    u16* wqkvb = wsb;
    u16* woutb = wqkvb + 786432;
    u16* wqb   = woutb + 262144;
    u16* wkb   = wqb + 65536;
    u16* xb    = wkb + 65536;
    u16* qkws  = xb + 4194304;

    // 5,373,952 f32 -> bf16 (weights + x), 4 elems/thread
    conv_kernel<<<5248, 256, 0, stream>>>(w_qkv, w_out, wq, wk, x, wsb);
    // QK: qk = x @ w_qkv[0:1024]^T + b_qkv  (128x128 tile) + fused qs/ks
    gemm_k<MQK, 8><<<dim3(64, 8), 256, 0, stream>>>(
        xb, 512, 0, wqkvb, b_qkv, nullptr, nullptr, qkws, nullptr, qs, ks);
    // stage 1 -> qg
    stage_soft<<<dim3(16, 64), 256, 0, stream>>>(
        qkws, 0, wqb, bq, nullptr, qs, nullptr, qg);
    // stage 2 -> kg
    stage_soft<<<dim3(16, 64), 256, 0, stream>>>(
        qkws, 512, wkb, bk, qg, qg, ks, kg);
    // VU: U = (x @ w_qkv[1024:]^T + bv) * kg  (into k-half of qk ws)
    gemm_k<MVU, 4><<<dim3(64, 8), 256, 0, stream>>>(
        xb, 512, 0, wqkvb + (size_t)1024 * 512, b_qkv + 1024, kg, nullptr, qkws, nullptr,
        nullptr, nullptr);
    // OUT: out = U @ w_out^T + b_out + qo
    gemm_k<MOUT, 4><<<dim3(64, 8), 256, 0, stream>>>(
        qkws, 1024, 512, woutb, b_out, nullptr, qkws, nullptr, out, nullptr, nullptr);
}